// Round 10
// baseline (475.756 us; speedup 1.0000x reference)
//
#include <hip/hip_runtime.h>
#include <math.h>

// B=128, H=W=40, C=60, L=1600, NH=10, HD=6, WS=8, N=64, NW=25, NB=4

typedef __bf16 bf16x8 __attribute__((ext_vector_type(8)));
typedef float f32x4 __attribute__((ext_vector_type(4)));
typedef unsigned int u32x4 __attribute__((ext_vector_type(4)));
typedef float f4u __attribute__((ext_vector_type(4), aligned(4)));

#define MFMA16(a, b, c) __builtin_amdgcn_mfma_f32_16x16x32_bf16(a, b, c, 0, 0, 0)

__device__ __forceinline__ unsigned short f2bf(float x) {  // RNE (prep only)
    unsigned u = __float_as_uint(x);
    return (unsigned short)((u + 0x7fffu + ((u >> 16) & 1u)) >> 16);
}
__device__ __forceinline__ unsigned short bfrn(float x) {  // 2 ops
    return (unsigned short)((__float_as_uint(x) + 0x8000u) >> 16);
}
__device__ __forceinline__ unsigned pk2rn(float a, float b) {  // 1 op
    unsigned r;
    asm("v_cvt_pk_bf16_f32 %0, %1, %2" : "=v"(r) : "v"(a), "v"(b));
    return r;
}
__device__ __forceinline__ float bfsel(unsigned u, int hi) {
    return __uint_as_float(hi ? (u & 0xffff0000u) : (u << 16));
}
__device__ __forceinline__ float gelu_f(float v) {
    float t2 = v * v;
    float e = __builtin_amdgcn_exp2f(v * fmaf(0.102943225f, t2, 2.302207877f));
    float r = __builtin_amdgcn_rcpf(e + 1.f);
    return fmaf(-v, r, v);
}
__device__ __forceinline__ int gidx(int n, int wh, int wc, int shift) {
    int hh = wh * 8 + (n >> 3) + shift; if (hh >= 40) hh -= 40;
    int ww = wc * 8 + (n & 7) + shift;  if (ww >= 40) ww -= 40;
    return hh * 40 + ww;
}

// ---------------------------------------------------------------- weight pre-pack (blocks)
__global__ __launch_bounds__(256) void prep_k(
    const float* __restrict__ qkvw, const float* __restrict__ pw,
    const float* __restrict__ f1w, const float* __restrict__ f2w,
    const float* __restrict__ qkvb, const float* __restrict__ pb,
    const float* __restrict__ f1b, const float* __restrict__ f2b,
    const float* __restrict__ g1v, const float* __restrict__ b1v,
    const float* __restrict__ g2v, const float* __restrict__ b2v,
    unsigned short* __restrict__ Wp)
{
    int t = blockIdx.x * 256 + threadIdx.x;  // 0..24575
    int lane = t & 63;
    int q6 = t >> 6;
    int layer = q6 / 96, tile = q6 % 96;
    int l15 = lane & 15, l4 = lane >> 4;
    const float* src; const float* gam = 0; const float* bet = 0;
    float bias = 0.f, rowscale = 1.f;
    int row, stride, rmax, kmax, k0;
    unsigned short* dst = Wp + layer * 49152;
    if (tile < 24) {
        int ot = tile >> 1, ks = tile & 1;
        src = qkvw + layer * 10800; row = ot * 16 + l15; k0 = ks * 32 + l4 * 8;
        rmax = 180; kmax = 60; stride = 60; dst += tile * 512;
        gam = g1v + layer * 60; bet = b1v + layer * 60;
        if (row < 180) bias = qkvb[layer * 180 + row];
        if (row < 60) rowscale = 0.58897780f;  // 6^-0.5 * log2(e)
    } else if (tile < 32) {
        int tt = tile - 24;
        src = pw + layer * 3600; row = (tt >> 1) * 16 + l15; k0 = (tt & 1) * 32 + l4 * 8;
        rmax = 60; kmax = 60; stride = 60; dst += 12288 + tt * 512;
        if (row < 60) bias = pb[layer * 60 + row];
    } else if (tile < 64) {
        int tt = tile - 32; int ks = tt & 1; int po = tt >> 1; int ot = po & 7; int ph = po >> 3;
        src = f1w + layer * 14400 + ph * 7200; row = ot * 16 + l15; k0 = ks * 32 + l4 * 8;
        rmax = 120; kmax = 60; stride = 60; dst += 16384 + tt * 512;
        gam = g2v + layer * 60; bet = b2v + layer * 60;
        if (row < 120) bias = f1b[layer * 240 + ph * 120 + row];
    } else {
        int tt = tile - 64; int ks = tt & 3; int po = tt >> 2; int ot = po & 3; int ph = po >> 2;
        src = f2w + layer * 14400 + ph * 120; row = ot * 16 + l15; k0 = ks * 32 + l4 * 8;
        rmax = 60; kmax = 120; stride = 240; dst += 32768 + tt * 512;
        if (ph == 0 && row < 60) bias = f2b[layer * 60 + row];
    }
    unsigned short v[8];
    #pragma unroll
    for (int i = 0; i < 8; i++) {
        int k = k0 + i;
        float f = 0.f;
        if (row < rmax) {
            if (k < kmax) {
                f = src[row * stride + k];
                if (gam) f *= gam[k];
            } else if (k == kmax) {
                f = bias;
                if (bet) for (int kk = 0; kk < kmax; kk++) f += src[row * stride + kk] * bet[kk];
            }
        }
        v[i] = f2bf(f * rowscale);
    }
    unsigned a0 = (unsigned)v[0] | ((unsigned)v[1] << 16);
    unsigned a1 = (unsigned)v[2] | ((unsigned)v[3] << 16);
    unsigned a2 = (unsigned)v[4] | ((unsigned)v[5] << 16);
    unsigned a3 = (unsigned)v[6] | ((unsigned)v[7] << 16);
    *(uint4*)(dst + lane * 8) = make_uint4(a0, a1, a2, a3);
}

// ---------------------------------------------------------------- conv weight pre-pack
__global__ __launch_bounds__(256) void prepc_k(
    const float* __restrict__ ciw, const float* __restrict__ cow,
    unsigned short* __restrict__ Wc)
{
    int t = blockIdx.x * 256 + threadIdx.x;
    if (t >= 3456) return;
    int lane = t & 63, tile = t >> 6;        // tile 0..53
    int l15 = lane & 15, l4 = lane >> 4;
    unsigned short v[8];
    if (tile < 36) {
        int mt = tile / 9, g = tile % 9;
        int ky = g / 3, kx = g % 3;
        int row = mt * 16 + l15;
        int ci0 = l4 * 8;
        #pragma unroll
        for (int i = 0; i < 8; i++) {
            int ci = ci0 + i;
            float f = (row < 60 && ci < 18) ? ciw[(row * 18 + ci) * 9 + ky * 3 + kx] : 0.f;
            v[i] = f2bf(f);
        }
    } else {
        int tt = tile - 36;
        int g = tt >> 1, ks = tt & 1;
        int row = l15;                        // co
        int ci0 = ks * 32 + l4 * 8;
        #pragma unroll
        for (int i = 0; i < 8; i++) {
            int ci = ci0 + i;
            float f = (row < 3 && ci < 60) ? cow[(row * 60 + ci) * 9 + g] : 0.f;
            v[i] = f2bf(f);
        }
    }
    unsigned a0 = (unsigned)v[0] | ((unsigned)v[1] << 16);
    unsigned a1 = (unsigned)v[2] | ((unsigned)v[3] << 16);
    unsigned a2 = (unsigned)v[4] | ((unsigned)v[5] << 16);
    unsigned a3 = (unsigned)v[6] | ((unsigned)v[7] << 16);
    *(uint4*)(Wc + tile * 512 + lane * 8) = make_uint4(a0, a1, a2, a3);
}

// ---------------------------------------------------------------- rpb pre-expansion
__global__ __launch_bounds__(256) void rpbexp_k(
    const float* __restrict__ rpb, unsigned* __restrict__ rpbE)
{
    int layer = blockIdx.x / 5, hp = blockIdx.x % 5;
    int tid = threadIdx.x;
    int q = tid >> 2, j0 = (tid & 3) * 16;
    const float* rsrc = rpb + layer * 2250 + hp * 2;
    unsigned* dst = rpbE + ((layer * 5 + hp) * 64 + q) * 64 + j0;
    int qr = q >> 3, qc = q & 7;
    #pragma unroll
    for (int jj = 0; jj < 16; jj++) {
        int j = j0 + jj;
        int jr = j >> 3, jc = j & 7;
        int ridx = ((qr - jr + 7) * 15 + (qc - jc + 7)) * 10;
        unsigned short lo = f2bf(rsrc[ridx] * 1.4426950409f);
        unsigned short hi = f2bf(rsrc[ridx + 1] * 1.4426950409f);
        dst[jj] = (unsigned)lo | ((unsigned)hi << 16);
    }
}

// ---------------------------------------------------------------- conv_in (implicit-GEMM MFMA)
__global__ __launch_bounds__(256) void conv_in_k(
    const float* __restrict__ x, const unsigned short* __restrict__ Wc,
    const float* __restrict__ bias, float* __restrict__ S)
{
    __shared__ __align__(16) unsigned short xt[10 * 42 * 32];  // 26880 B
    int b = blockIdx.x / 5, y0 = (blockIdx.x % 5) * 8;
    int tid = threadIdx.x;
    int lane = tid & 63, w = tid >> 6;
    int l15 = lane & 15, l4 = lane >> 4;

    uint4* xt4 = (uint4*)xt;
    for (int i = tid; i < 1680; i += 256) xt4[i] = make_uint4(0u, 0u, 0u, 0u);
    __syncthreads();

    const float* xb = x + (size_t)b * 28800;
    for (int idx = tid; idx < 10 * 18 * 40; idx += 256) {
        int xx = idx % 40;
        int rem = idx / 40;
        int ci = rem % 18;
        int ry = rem / 18;
        int yy = y0 + ry - 1;
        if (yy >= 0 && yy < 40) {
            float v = xb[ci * 1600 + yy * 40 + xx];
            int xs = xx + 1;
            int bo = (((ry * 42 + xs) * 32 + ci) * 2) ^ ((xs & 3) << 4);
            *(unsigned short*)((char*)xt + bo) = bfrn(v);
        }
    }
    __syncthreads();

    bf16x8 afr[9];
    #pragma unroll
    for (int g = 0; g < 9; g++)
        afr[g] = *(const bf16x8*)(Wc + (w * 9 + g) * 512 + lane * 8);

    int c0 = w * 16 + l4 * 4;
    bool valid = (c0 < 60);
    f4u bv = {0.f, 0.f, 0.f, 0.f};
    if (valid) bv = *(const f4u*)(bias + c0);
    const f32x4 zf = {0.f, 0.f, 0.f, 0.f};
    const char* xtb = (const char*)xt;

    for (int nt = 0; nt < 20; nt++) {
        int tok = nt * 16 + l15;
        int yl = tok / 40, xl = tok % 40;
        f32x4 acc = zf;
        #pragma unroll
        for (int g = 0; g < 9; g++) {
            int ky = g / 3, kx = g % 3;
            int xs = xl + kx;
            int ba = ((yl + ky) * 42 + xs) * 64 + ((l4 ^ (xs & 3)) << 4);
            bf16x8 bfrag = *(const bf16x8*)(xtb + ba);
            acc = MFMA16(afr[g], bfrag, acc);
        }
        if (valid) {
            float4 r;
            r.x = acc[0] + bv[0]; r.y = acc[1] + bv[1];
            r.z = acc[2] + bv[2]; r.w = acc[3] + bv[3];
            *(float4*)(S + ((size_t)b * 1600 + y0 * 40 + tok) * 60 + c0) = r;
        }
    }
}

// ---------------------------------------------------------------- fused Swin block
// LDS 38016 B -> 4 blocks/CU. x1 residual in regs; per-head K/Q preloaded one ahead;
// no manual lgkm drains (compiler inserts counted waits for same-wave P RAW).
struct KQf { bf16x8 bq, ak0, ak1, ak2, ak3; };

template<int SHIFT>
__global__ __launch_bounds__(256, 4) void block_k(
    float* __restrict__ S,
    const unsigned short* __restrict__ WpL,
    const unsigned* __restrict__ rpE)
{
    __shared__ __align__(16) unsigned char LDSA[38016];
    unsigned short* xln = (unsigned short*)(LDSA + 0);
    unsigned short* Pl  = (unsigned short*)(LDSA + 0);
    unsigned short* h1  = (unsigned short*)(LDSA + 0);
    unsigned short* qn  = (unsigned short*)(LDSA + 9216);
    unsigned short* kn  = (unsigned short*)(LDSA + 18432);
    unsigned short* vt  = (unsigned short*)(LDSA + 27648);
    unsigned short* ln2 = (unsigned short*)(LDSA + 27648);

    const int tid = threadIdx.x;
    const int lane = tid & 63, w = tid >> 6;
    const int l15 = lane & 15, l4 = lane >> 4;
    const int wbase = w * 16;
    const int b = blockIdx.x / 25, wnd = blockIdx.x % 25;
    const int wh = wnd / 5, wc = wnd % 5;
    float* Sb = S + (size_t)b * 96000;
    const f32x4 zf = {0.f, 0.f, 0.f, 0.f};
    u32x4 zu = {0u, 0u, 0u, 0u};
    const bf16x8 zb = __builtin_bit_cast(bf16x8, zu);
    u32x4 ou = {0x3F803F80u, 0x3F803F80u, 0x3F803F80u, 0x3F803F80u};
    const bf16x8 ones = __builtin_bit_cast(bf16x8, ou);

    // ---- LN1 -> xln (bf16 n-major; col60=1 bias slot)
    {
        int n = tid >> 2, p = tid & 3, cb = p * 16;
        int g = gidx(n, wh, wc, SHIFT);
        const float* xp = Sb + (size_t)g * 60 + cb;
        float xv[16];
        {
            float4 v0 = *(const float4*)xp;
            float4 v1 = *(const float4*)(xp + 4);
            float4 v2 = *(const float4*)(xp + 8);
            xv[0] = v0.x; xv[1] = v0.y; xv[2] = v0.z; xv[3] = v0.w;
            xv[4] = v1.x; xv[5] = v1.y; xv[6] = v1.z; xv[7] = v1.w;
            xv[8] = v2.x; xv[9] = v2.y; xv[10] = v2.z; xv[11] = v2.w;
            if (p < 3) {
                float4 v3 = *(const float4*)(xp + 12);
                xv[12] = v3.x; xv[13] = v3.y; xv[14] = v3.z; xv[15] = v3.w;
            } else { xv[12] = xv[13] = xv[14] = xv[15] = 0.f; }
        }
        float s = 0.f;
        #pragma unroll
        for (int ii = 0; ii < 16; ii++) s += xv[ii];
        s += __shfl_xor(s, 1); s += __shfl_xor(s, 2);
        float mean = s * (1.f / 60.f);
        float vv = 0.f;
        #pragma unroll
        for (int ii = 0; ii < 12; ii++) { float d = xv[ii] - mean; vv += d * d; }
        #pragma unroll
        for (int ii = 12; ii < 16; ii++) { float d = xv[ii] - mean; vv += (p < 3) ? d * d : 0.f; }
        vv += __shfl_xor(vv, 1); vv += __shfl_xor(vv, 2);
        float rs = rsqrtf(vv * (1.f / 60.f) + 1e-5f);
        float ov[16];
        #pragma unroll
        for (int ii = 0; ii < 12; ii++) ov[ii] = (xv[ii] - mean) * rs;
        #pragma unroll
        for (int ii = 12; ii < 16; ii++)
            ov[ii] = (p < 3) ? (xv[ii] - mean) * rs : ((ii == 12) ? 1.f : 0.f);
        unsigned short* xr = xln + n * 72 + cb;
        *(uint4*)xr = make_uint4(pk2rn(ov[0], ov[1]), pk2rn(ov[2], ov[3]),
                                 pk2rn(ov[4], ov[5]), pk2rn(ov[6], ov[7]));
        *(uint4*)(xr + 8) = make_uint4(pk2rn(ov[8], ov[9]), pk2rn(ov[10], ov[11]),
                                       pk2rn(ov[12], ov[13]), pk2rn(ov[14], ov[15]));
    }
    __syncthreads();  // B1

    // ---- QKV (bias in k=60 slot; q pre-scaled)
    {
        bf16x8 bx[4][2];
        #pragma unroll
        for (int nt = 0; nt < 4; nt++)
            #pragma unroll
            for (int ks = 0; ks < 2; ks++)
                bx[nt][ks] = *(const bf16x8*)(xln + (nt * 16 + l15) * 72 + l4 * 8 + ks * 32);
        #pragma unroll
        for (int t = 0; t < 3; t++) {
            int ot = w * 3 + t;
            f32x4 acc[4];
            #pragma unroll
            for (int nt = 0; nt < 4; nt++) acc[nt] = zf;
            #pragma unroll
            for (int ks = 0; ks < 2; ks++) {
                bf16x8 a = *(const bf16x8*)(WpL + (ot * 2 + ks) * 512 + lane * 8);
                #pragma unroll
                for (int nt = 0; nt < 4; nt++) acc[nt] = MFMA16(a, bx[nt][ks], acc[nt]);
            }
            int o0 = ot * 16 + l4 * 4;
            #pragma unroll
            for (int nt = 0; nt < 4; nt++) {
                int n = nt * 16 + l15;
                if (o0 < 60) {
                    *(uint2*)(qn + n * 72 + o0) =
                        make_uint2(pk2rn(acc[nt][0], acc[nt][1]), pk2rn(acc[nt][2], acc[nt][3]));
                } else if (o0 < 120) {
                    *(uint2*)(kn + n * 72 + (o0 - 60)) =
                        make_uint2(pk2rn(acc[nt][0], acc[nt][1]), pk2rn(acc[nt][2], acc[nt][3]));
                } else {
                    int r = o0 - 120;
                    vt[(r + 0) * 72 + n] = bfrn(acc[nt][0]);
                    vt[(r + 1) * 72 + n] = bfrn(acc[nt][1]);
                    vt[(r + 2) * 72 + n] = bfrn(acc[nt][2]);
                    vt[(r + 3) * 72 + n] = bfrn(acc[nt][3]);
                }
            }
        }
    }
    __syncthreads();  // B2 (xln dead -> Pl writable)

    // ---- shift-mask bits
    unsigned maskbits = 0u;
    if (SHIFT) {
        int qtok = wbase + l15;
        int qr = qtok >> 3, qc = qtok & 7;
        int shp = wh * 8 + qr, swp = wc * 8 + qc;
        int qreg = (shp < 32 ? 0 : (shp < 36 ? 1 : 2)) * 3 + (swp < 32 ? 0 : (swp < 36 ? 1 : 2));
        #pragma unroll
        for (int e = 0; e < 16; e++) {
            int jt = e >> 2, r = e & 3;
            int j = jt * 16 + l4 * 4 + r;
            int jr = j >> 3, jc = j & 7;
            int shq = wh * 8 + jr, swq = wc * 8 + jc;
            int jreg = (shq < 32 ? 0 : (shq < 36 ? 1 : 2)) * 3 + (swq < 32 ? 0 : (swq < 36 ? 1 : 2));
            if (jreg != qreg) maskbits |= (1u << e);
        }
    }

    // ---- head loop (software-pipelined K/Q preload; per-wave P rows; no manual drains)
    f32x4 oacc[10];
    #pragma unroll
    for (int h = 0; h < 10; h++) oacc[h] = zf;
    unsigned short* prow = Pl + (wbase + l15) * 72;
    const unsigned* rpq = rpE + ((wbase + l15) << 6) + (l4 << 2);

    u32x4 rpc[4];
    #pragma unroll
    for (int jt = 0; jt < 4; jt++) rpc[jt] = *(const u32x4*)(rpq + jt * 16);

    KQf kq;
    kq.bq = zb; kq.ak0 = zb; kq.ak1 = zb; kq.ak2 = zb; kq.ak3 = zb;
    if (l4 == 0) {
        const unsigned* qp = (const unsigned*)(qn + (wbase + l15) * 72);
        u32x4 uq = {qp[0], qp[1], qp[2], 0u};
        kq.bq = __builtin_bit_cast(bf16x8, uq);
        const unsigned* k0p = (const unsigned*)(kn + (0 * 16 + l15) * 72);
        const unsigned* k1p = (const unsigned*)(kn + (1 * 16 + l15) * 72);
        const unsigned* k2p = (const unsigned*)(kn + (2 * 16 + l15) * 72);
        const unsigned* k3p = (const unsigned*)(kn + (3 * 16 + l15) * 72);
        u32x4 u0 = {k0p[0], k0p[1], k0p[2], 0u}; kq.ak0 = __builtin_bit_cast(bf16x8, u0);
        u32x4 u1 = {k1p[0], k1p[1], k1p[2], 0u}; kq.ak1 = __builtin_bit_cast(bf16x8, u1);
        u32x4 u2 = {k2p[0], k2p[1], k2p[2], 0u}; kq.ak2 = __builtin_bit_cast(bf16x8, u2);
        u32x4 u3 = {k3p[0], k3p[1], k3p[2], 0u}; kq.ak3 = __builtin_bit_cast(bf16x8, u3);
    }

    #pragma unroll
    for (int hp = 0; hp < 5; hp++) {
        u32x4 rpn[4];
        if (hp < 4) {
            const unsigned* rq = rpq + (hp + 1) * 4096;
            #pragma unroll
            for (int jt = 0; jt < 4; jt++) rpn[jt] = *(const u32x4*)(rq + jt * 16);
        }
        #pragma unroll
        for (int hh2 = 0; hh2 < 2; hh2++) {
            const int h = hp * 2 + hh2;
            // scores for head h (operands preloaded)
            f32x4 s0 = MFMA16(kq.ak0, kq.bq, zf);
            f32x4 s1 = MFMA16(kq.ak1, kq.bq, zf);
            f32x4 s2 = MFMA16(kq.ak2, kq.bq, zf);
            f32x4 s3 = MFMA16(kq.ak3, kq.bq, zf);
            // issue K/Q loads for head h+1 now (before P writes -> overlap)
            KQf kqn;
            kqn.bq = zb; kqn.ak0 = zb; kqn.ak1 = zb; kqn.ak2 = zb; kqn.ak3 = zb;
            if (h < 9 && l4 == 0) {
                int hc = (h + 1) * 6;
                const unsigned* qp = (const unsigned*)(qn + (wbase + l15) * 72 + hc);
                u32x4 uq = {qp[0], qp[1], qp[2], 0u};
                kqn.bq = __builtin_bit_cast(bf16x8, uq);
                const unsigned* k0p = (const unsigned*)(kn + (0 * 16 + l15) * 72 + hc);
                const unsigned* k1p = (const unsigned*)(kn + (1 * 16 + l15) * 72 + hc);
                const unsigned* k2p = (const unsigned*)(kn + (2 * 16 + l15) * 72 + hc);
                const unsigned* k3p = (const unsigned*)(kn + (3 * 16 + l15) * 72 + hc);
                u32x4 u0 = {k0p[0], k0p[1], k0p[2], 0u}; kqn.ak0 = __builtin_bit_cast(bf16x8, u0);
                u32x4 u1 = {k1p[0], k1p[1], k1p[2], 0u}; kqn.ak1 = __builtin_bit_cast(bf16x8, u1);
                u32x4 u2 = {k2p[0], k2p[1], k2p[2], 0u}; kqn.ak2 = __builtin_bit_cast(bf16x8, u2);
                u32x4 u3 = {k3p[0], k3p[1], k3p[2], 0u}; kqn.ak3 = __builtin_bit_cast(bf16x8, u3);
            }
            float ee[16];
            #pragma unroll
            for (int r = 0; r < 4; r++) {
                ee[0 + r]  = __builtin_amdgcn_exp2f(s0[r] + bfsel(rpc[0][r], hh2));
                ee[4 + r]  = __builtin_amdgcn_exp2f(s1[r] + bfsel(rpc[1][r], hh2));
                ee[8 + r]  = __builtin_amdgcn_exp2f(s2[r] + bfsel(rpc[2][r], hh2));
                ee[12 + r] = __builtin_amdgcn_exp2f(s3[r] + bfsel(rpc[3][r], hh2));
            }
            if (SHIFT) {
                #pragma unroll
                for (int e = 0; e < 16; e++)
                    if (maskbits & (1u << e)) ee[e] = 0.f;
            }
            #pragma unroll
            for (int jt = 0; jt < 4; jt++)
                *(uint2*)(prow + jt * 16 + l4 * 4) =
                    make_uint2(pk2rn(ee[jt * 4 + 0], ee[jt * 4 + 1]),
                               pk2rn(ee[jt * 4 + 2], ee[jt * 4 + 3]));
            // compiler inserts counted lgkm wait for same-wave P RAW
            bf16x8 ap0 = *(const bf16x8*)(prow + l4 * 8);
            bf16x8 ap1 = *(const bf16x8*)(prow + 32 + l4 * 8);
            bf16x8 bv0 = *(const bf16x8*)(vt + (h * 6 + l15) * 72 + l4 * 8);
            bf16x8 bv1 = *(const bf16x8*)(vt + (h * 6 + l15) * 72 + 32 + l4 * 8);
            f32x4 sm = MFMA16(ap0, ones, zf);
            sm = MFMA16(ap1, ones, sm);
            f32x4 pv = MFMA16(ap0, bv0, zf);
            pv = MFMA16(ap1, bv1, pv);
            #pragma unroll
            for (int r = 0; r < 4; r++)
                oacc[h][r] = pv[r] * __builtin_amdgcn_rcpf(sm[r]);
            kq = kqn;
        }
        #pragma unroll
        for (int jt = 0; jt < 4; jt++) rpc[jt] = rpn[jt];
    }

    // ---- attention out -> olds (=qn slab; own-wave rows only, no barrier needed)
    unsigned short* olds = qn;
    if (l15 < 6) {
        #pragma unroll
        for (int h = 0; h < 10; h++)
            #pragma unroll
            for (int j = 0; j < 4; j++)
                olds[(wbase + l4 * 4 + j) * 72 + h * 6 + l15] = bfrn(oacc[h][j]);
    } else if (l15 < 10) {
        unsigned short pv16 = (l15 == 6) ? (unsigned short)0x3F80 : (unsigned short)0;
        #pragma unroll
        for (int j = 0; j < 4; j++)
            olds[(wbase + l4 * 4 + j) * 72 + 60 + (l15 - 6)] = pv16;
    }

    // ---- proj + residual -> x1 in REGISTERS (reads own olds rows; still no barrier)
    f32x4 x1v[4];
    {
        bf16x8 bo0 = *(const bf16x8*)(olds + (wbase + l15) * 72 + l4 * 8);
        bf16x8 bo1 = *(const bf16x8*)(olds + (wbase + l15) * 72 + 32 + l4 * 8);
        f32x4 acc[4];
        #pragma unroll
        for (int ot = 0; ot < 4; ot++) acc[ot] = zf;
        #pragma unroll
        for (int ot = 0; ot < 4; ot++) {
            bf16x8 a0 = *(const bf16x8*)(WpL + 12288 + (ot * 2 + 0) * 512 + lane * 8);
            bf16x8 a1 = *(const bf16x8*)(WpL + 12288 + (ot * 2 + 1) * 512 + lane * 8);
            acc[ot] = MFMA16(a0, bo0, acc[ot]);
            acc[ot] = MFMA16(a1, bo1, acc[ot]);
        }
        int n = wbase + l15;
        int g = gidx(n, wh, wc, SHIFT);
        #pragma unroll
        for (int ot = 0; ot < 4; ot++) {
            int o0 = ot * 16 + l4 * 4;
            if (o0 < 60) {
                float4 xr = *(const float4*)(Sb + (size_t)g * 60 + o0);
                x1v[ot][0] = xr.x + acc[ot][0];
                x1v[ot][1] = xr.y + acc[ot][1];
                x1v[ot][2] = xr.z + acc[ot][2];
                x1v[ot][3] = xr.w + acc[ot][3];
            } else {
                x1v[ot] = zf;
            }
        }
    }
    __syncthreads();  // B2.5: all waves past vt/kn reads -> ln2 overlay safe

    // ---- LN2 in registers -> ln2 (bf16)
    {
        float s = 0.f;
        #pragma unroll
        for (int ot = 0; ot < 4; ot++)
            #pragma unroll
            for (int r = 0; r < 4; r++) s += x1v[ot][r];
        s += __shfl_xor(s, 16); s += __shfl_xor(s, 32);
        float mean = s * (1.f / 60.f);
        float vv = 0.f;
        #pragma unroll
        for (int ot = 0; ot < 4; ot++) {
            int o0 = ot * 16 + l4 * 4;
            if (o0 < 60) {
                #pragma unroll
                for (int r = 0; r < 4; r++) { float d = x1v[ot][r] - mean; vv += d * d; }
            }
        }
        vv += __shfl_xor(vv, 16); vv += __shfl_xor(vv, 32);
        float rs = rsqrtf(vv * (1.f / 60.f) + 1e-5f);
        int n = wbase + l15;
        #pragma unroll
        for (int ot = 0; ot < 4; ot++) {
            int o0 = ot * 16 + l4 * 4;
            if (o0 < 60) {
                *(uint2*)(ln2 + n * 72 + o0) = make_uint2(
                    pk2rn((x1v[ot][0] - mean) * rs, (x1v[ot][1] - mean) * rs),
                    pk2rn((x1v[ot][2] - mean) * rs, (x1v[ot][3] - mean) * rs));
            } else {
                *(uint2*)(ln2 + n * 72 + 60) = make_uint2(0x00003F80u, 0u);  // bias=1, pad 0
            }
        }
    }
    __syncthreads();  // B3 (ln2 ready; Pl/olds dead -> h1 overlay safe)

    // ---- MLP (x1 stays in regs for the final residual)
    f32x4 acc2[4];
    #pragma unroll
    for (int ot = 0; ot < 4; ot++) acc2[ot] = zf;

    #pragma unroll
    for (int ph = 0; ph < 2; ph++) {
        {
            bf16x8 bl[4][2];
            #pragma unroll
            for (int nt = 0; nt < 4; nt++)
                #pragma unroll
                for (int ks = 0; ks < 2; ks++)
                    bl[nt][ks] = *(const bf16x8*)(ln2 + (nt * 16 + l15) * 72 + l4 * 8 + ks * 32);
            #pragma unroll
            for (int t = 0; t < 2; t++) {
                int ot = w + t * 4;
                f32x4 a1[4];
                #pragma unroll
                for (int nt = 0; nt < 4; nt++) a1[nt] = zf;
                #pragma unroll
                for (int ks = 0; ks < 2; ks++) {
                    bf16x8 a = *(const bf16x8*)(WpL + 16384 + ((ph * 8 + ot) * 2 + ks) * 512 + lane * 8);
                    #pragma unroll
                    for (int nt = 0; nt < 4; nt++) a1[nt] = MFMA16(a, bl[nt][ks], a1[nt]);
                }
                int o0 = ot * 16 + l4 * 4;
                if (o0 < 120) {
                    #pragma unroll
                    for (int nt = 0; nt < 4; nt++) {
                        int n = nt * 16 + l15;
                        *(uint2*)(h1 + n * 136 + o0) =
                            make_uint2(pk2rn(gelu_f(a1[nt][0]), gelu_f(a1[nt][1])),
                                       pk2rn(gelu_f(a1[nt][2]), gelu_f(a1[nt][3])));
                    }
                }
            }
            if (ph == 0 && tid < 64)
                *(uint4*)(h1 + tid * 136 + 120) = make_uint4(0x3F80u, 0u, 0u, 0u);
        }
        __syncthreads();
        {
            bf16x8 bh[4];
            #pragma unroll
            for (int ks = 0; ks < 4; ks++)
                bh[ks] = *(const bf16x8*)(h1 + (wbase + l15) * 136 + l4 * 8 + ks * 32);
            #pragma unroll
            for (int ot = 0; ot < 4; ot++)
                #pragma unroll
                for (int ks = 0; ks < 4; ks++) {
                    bf16x8 a = *(const bf16x8*)(WpL + 32768 + ((ph * 4 + ot) * 4 + ks) * 512 + lane * 8);
                    acc2[ot] = MFMA16(a, bh[ks], acc2[ot]);
                }
        }
        if (ph == 0) __syncthreads();
    }

    // ---- final: S[g] = x1(reg) + fc2out
    {
        int n = wbase + l15;
        int g = gidx(n, wh, wc, SHIFT);
        #pragma unroll
        for (int ot = 0; ot < 4; ot++) {
            int o0 = ot * 16 + l4 * 4;
            if (o0 < 60) {
                float4 r;
                r.x = x1v[ot][0] + acc2[ot][0];
                r.y = x1v[ot][1] + acc2[ot][1];
                r.z = x1v[ot][2] + acc2[ot][2];
                r.w = x1v[ot][3] + acc2[ot][3];
                *(float4*)(Sb + (size_t)g * 60 + o0) = r;
            }
        }
    }
}

// ---------------------------------------------------------------- conv_out (implicit-GEMM MFMA)
__global__ __launch_bounds__(256) void conv_out_k(
    const float* __restrict__ S, const unsigned short* __restrict__ Wc2,
    const float* __restrict__ bias, float* __restrict__ out)
{
    __shared__ __align__(16) unsigned short st[6 * 42 * 64];  // 32256 B
    int b = blockIdx.x / 10, y0 = (blockIdx.x % 10) * 4;
    int tid = threadIdx.x;
    int lane = tid & 63, w = tid >> 6;
    int l15 = lane & 15, l4 = lane >> 4;

    uint4* st4 = (uint4*)st;
    for (int i = tid; i < 2016; i += 256) st4[i] = make_uint4(0u, 0u, 0u, 0u);
    __syncthreads();

    const float* Sb = S + (size_t)b * 96000;
    for (int idx = tid; idx < 3600; idx += 256) {
        int cg = idx % 15;
        int xx = (idx / 15) % 40;
        int ry = idx / 600;
        int yy = y0 + ry - 1;
        if (yy >= 0 && yy < 40) {
            const float* sp = Sb + ((size_t)yy * 40 + xx) * 60 + cg * 4;
            float4 v = *(const float4*)sp;
            int xs = xx + 1;
            int bo = (ry * 42 + xs) * 128 + ((cg * 8) ^ ((xs & 7) << 4));
            *(uint2*)((char*)st + bo) = make_uint2(pk2rn(v.x, v.y), pk2rn(v.z, v.w));
        }
    }
    __syncthreads();

    bf16x8 afr[9][2];
    #pragma unroll
    for (int g = 0; g < 9; g++)
        #pragma unroll
        for (int ks = 0; ks < 2; ks++)
            afr[g][ks] = *(const bf16x8*)(Wc2 + (g * 2 + ks) * 512 + lane * 8);

    float b0 = bias[0], b1 = bias[1], b2 = bias[2];
    const f32x4 zf = {0.f, 0.f, 0.f, 0.f};
    const char* stb = (const char*)st;

    for (int nt = w; nt < 10; nt += 4) {
        int tok = nt * 16 + l15;
        int yl = tok / 40, xl = tok % 40;
        f32x4 acc = zf;
        #pragma unroll
        for (int g = 0; g < 9; g++) {
            int ky = g / 3, kx = g % 3;
            int xs = xl + kx;
            int base = ((yl + ky) * 42 + xs) * 128;
            #pragma unroll
            for (int ks = 0; ks < 2; ks++) {
                int bo = base + (((ks * 4 + l4) ^ (xs & 7)) << 4);
                bf16x8 bfrag = *(const bf16x8*)(stb + bo);
                acc = MFMA16(afr[g][ks], bfrag, acc);
            }
        }
        if (l4 == 0) {
            int y = y0 + yl;
            float* op = out + (size_t)b * 4800 + y * 40 + xl;
            op[0] = acc[0] + b0;
            op[1600] = acc[1] + b1;
            op[3200] = acc[2] + b2;
        }
    }
}

// ---------------------------------------------------------------- launch
extern "C" void kernel_launch(void* const* d_in, const int* in_sizes, int n_in,
                              void* d_out, int out_size, void* d_ws, size_t ws_size,
                              hipStream_t stream)
{
    const float* x   = (const float*)d_in[0];
    const float* ciw = (const float*)d_in[1];
    const float* cib = (const float*)d_in[2];
    const float* n1g = (const float*)d_in[3];
    const float* n1b = (const float*)d_in[4];
    const float* qw  = (const float*)d_in[5];
    const float* qb  = (const float*)d_in[6];
    const float* rpb = (const float*)d_in[7];
    const float* pw  = (const float*)d_in[8];
    const float* pb  = (const float*)d_in[9];
    const float* n2g = (const float*)d_in[10];
    const float* n2b = (const float*)d_in[11];
    const float* f1w = (const float*)d_in[12];
    const float* f1b = (const float*)d_in[13];
    const float* f2w = (const float*)d_in[14];
    const float* f2b = (const float*)d_in[15];
    const float* cow = (const float*)d_in[16];
    const float* cob = (const float*)d_in[17];
    float* out = (float*)d_out;
    float* S = (float*)d_ws;                                        // 49,152,000 B
    unsigned short* Wp = (unsigned short*)((char*)d_ws + 49152000); // packed weights
    unsigned* rpbE = (unsigned*)((char*)d_ws + 49545216);           // expanded rpb
    unsigned short* Wc = (unsigned short*)((char*)d_ws + 49872896); // conv A-frags

    prep_k<<<96, 256, 0, stream>>>(qw, pw, f1w, f2w, qb, pb, f1b, f2b,
                                   n1g, n1b, n2g, n2b, Wp);
    prepc_k<<<14, 256, 0, stream>>>(ciw, cow, Wc);
    rpbexp_k<<<20, 256, 0, stream>>>(rpb, rpbE);
    conv_in_k<<<128 * 5, 256, 0, stream>>>(x, Wc, cib, S);
    for (int i = 0; i < 4; i++) {
        const unsigned short* WpL = Wp + i * 49152;
        const unsigned* rpEL = rpbE + i * 5 * 4096;
        if (i & 1) block_k<4><<<128 * 25, 256, 0, stream>>>(S, WpL, rpEL);
        else       block_k<0><<<128 * 25, 256, 0, stream>>>(S, WpL, rpEL);
    }
    conv_out_k<<<128 * 10, 256, 0, stream>>>(S, Wc + 36 * 512, cob, out);
}

// Round 11
// 392.672 us; speedup vs baseline: 1.2116x; 1.2116x over previous
//
#include <hip/hip_runtime.h>
#include <math.h>

// B=128, H=W=40, C=60, L=1600, NH=10, HD=6, WS=8, N=64, NW=25, NB=4

typedef __bf16 bf16x8 __attribute__((ext_vector_type(8)));
typedef float f32x4 __attribute__((ext_vector_type(4)));
typedef unsigned int u32x4 __attribute__((ext_vector_type(4)));
typedef float f4u __attribute__((ext_vector_type(4), aligned(4)));

#define MFMA16(a, b, c) __builtin_amdgcn_mfma_f32_16x16x32_bf16(a, b, c, 0, 0, 0)

__device__ __forceinline__ unsigned short f2bf(float x) {  // RNE (prep only)
    unsigned u = __float_as_uint(x);
    return (unsigned short)((u + 0x7fffu + ((u >> 16) & 1u)) >> 16);
}
__device__ __forceinline__ unsigned short bfrn(float x) {  // 2 ops
    return (unsigned short)((__float_as_uint(x) + 0x8000u) >> 16);
}
__device__ __forceinline__ unsigned pk2rn(float a, float b) {  // 1 op
    unsigned r;
    asm("v_cvt_pk_bf16_f32 %0, %1, %2" : "=v"(r) : "v"(a), "v"(b));
    return r;
}
__device__ __forceinline__ float bfsel(unsigned u, int hi) {
    return __uint_as_float(hi ? (u & 0xffff0000u) : (u << 16));
}
__device__ __forceinline__ float gelu_f(float v) {
    float t2 = v * v;
    float e = __builtin_amdgcn_exp2f(v * fmaf(0.102943225f, t2, 2.302207877f));
    float r = __builtin_amdgcn_rcpf(e + 1.f);
    return fmaf(-v, r, v);
}
__device__ __forceinline__ int gidx(int n, int wh, int wc, int shift) {
    int hh = wh * 8 + (n >> 3) + shift; if (hh >= 40) hh -= 40;
    int ww = wc * 8 + (n & 7) + shift;  if (ww >= 40) ww -= 40;
    return hh * 40 + ww;
}

// ---------------------------------------------------------------- weight pre-pack (blocks)
__global__ __launch_bounds__(256) void prep_k(
    const float* __restrict__ qkvw, const float* __restrict__ pw,
    const float* __restrict__ f1w, const float* __restrict__ f2w,
    const float* __restrict__ qkvb, const float* __restrict__ pb,
    const float* __restrict__ f1b, const float* __restrict__ f2b,
    const float* __restrict__ g1v, const float* __restrict__ b1v,
    const float* __restrict__ g2v, const float* __restrict__ b2v,
    unsigned short* __restrict__ Wp)
{
    int t = blockIdx.x * 256 + threadIdx.x;  // 0..24575
    int lane = t & 63;
    int q6 = t >> 6;
    int layer = q6 / 96, tile = q6 % 96;
    int l15 = lane & 15, l4 = lane >> 4;
    const float* src; const float* gam = 0; const float* bet = 0;
    float bias = 0.f, rowscale = 1.f;
    int row, stride, rmax, kmax, k0;
    unsigned short* dst = Wp + layer * 49152;
    if (tile < 24) {
        int ot = tile >> 1, ks = tile & 1;
        src = qkvw + layer * 10800; row = ot * 16 + l15; k0 = ks * 32 + l4 * 8;
        rmax = 180; kmax = 60; stride = 60; dst += tile * 512;
        gam = g1v + layer * 60; bet = b1v + layer * 60;
        if (row < 180) bias = qkvb[layer * 180 + row];
        if (row < 60) rowscale = 0.58897780f;  // 6^-0.5 * log2(e)
    } else if (tile < 32) {
        int tt = tile - 24;
        src = pw + layer * 3600; row = (tt >> 1) * 16 + l15; k0 = (tt & 1) * 32 + l4 * 8;
        rmax = 60; kmax = 60; stride = 60; dst += 12288 + tt * 512;
        if (row < 60) bias = pb[layer * 60 + row];
    } else if (tile < 64) {
        int tt = tile - 32; int ks = tt & 1; int po = tt >> 1; int ot = po & 7; int ph = po >> 3;
        src = f1w + layer * 14400 + ph * 7200; row = ot * 16 + l15; k0 = ks * 32 + l4 * 8;
        rmax = 120; kmax = 60; stride = 60; dst += 16384 + tt * 512;
        gam = g2v + layer * 60; bet = b2v + layer * 60;
        if (row < 120) bias = f1b[layer * 240 + ph * 120 + row];
    } else {
        int tt = tile - 64; int ks = tt & 3; int po = tt >> 2; int ot = po & 3; int ph = po >> 2;
        src = f2w + layer * 14400 + ph * 120; row = ot * 16 + l15; k0 = ks * 32 + l4 * 8;
        rmax = 60; kmax = 120; stride = 240; dst += 32768 + tt * 512;
        if (ph == 0 && row < 60) bias = f2b[layer * 60 + row];
    }
    unsigned short v[8];
    #pragma unroll
    for (int i = 0; i < 8; i++) {
        int k = k0 + i;
        float f = 0.f;
        if (row < rmax) {
            if (k < kmax) {
                f = src[row * stride + k];
                if (gam) f *= gam[k];
            } else if (k == kmax) {
                f = bias;
                if (bet) for (int kk = 0; kk < kmax; kk++) f += src[row * stride + kk] * bet[kk];
            }
        }
        v[i] = f2bf(f * rowscale);
    }
    unsigned a0 = (unsigned)v[0] | ((unsigned)v[1] << 16);
    unsigned a1 = (unsigned)v[2] | ((unsigned)v[3] << 16);
    unsigned a2 = (unsigned)v[4] | ((unsigned)v[5] << 16);
    unsigned a3 = (unsigned)v[6] | ((unsigned)v[7] << 16);
    *(uint4*)(dst + lane * 8) = make_uint4(a0, a1, a2, a3);
}

// ---------------------------------------------------------------- conv weight pre-pack
__global__ __launch_bounds__(256) void prepc_k(
    const float* __restrict__ ciw, const float* __restrict__ cow,
    unsigned short* __restrict__ Wc)
{
    int t = blockIdx.x * 256 + threadIdx.x;
    if (t >= 3456) return;
    int lane = t & 63, tile = t >> 6;        // tile 0..53
    int l15 = lane & 15, l4 = lane >> 4;
    unsigned short v[8];
    if (tile < 36) {
        int mt = tile / 9, g = tile % 9;
        int ky = g / 3, kx = g % 3;
        int row = mt * 16 + l15;
        int ci0 = l4 * 8;
        #pragma unroll
        for (int i = 0; i < 8; i++) {
            int ci = ci0 + i;
            float f = (row < 60 && ci < 18) ? ciw[(row * 18 + ci) * 9 + ky * 3 + kx] : 0.f;
            v[i] = f2bf(f);
        }
    } else {
        int tt = tile - 36;
        int g = tt >> 1, ks = tt & 1;
        int row = l15;                        // co
        int ci0 = ks * 32 + l4 * 8;
        #pragma unroll
        for (int i = 0; i < 8; i++) {
            int ci = ci0 + i;
            float f = (row < 3 && ci < 60) ? cow[(row * 60 + ci) * 9 + g] : 0.f;
            v[i] = f2bf(f);
        }
    }
    unsigned a0 = (unsigned)v[0] | ((unsigned)v[1] << 16);
    unsigned a1 = (unsigned)v[2] | ((unsigned)v[3] << 16);
    unsigned a2 = (unsigned)v[4] | ((unsigned)v[5] << 16);
    unsigned a3 = (unsigned)v[6] | ((unsigned)v[7] << 16);
    *(uint4*)(Wc + tile * 512 + lane * 8) = make_uint4(a0, a1, a2, a3);
}

// ---------------------------------------------------------------- rpb pre-expansion
__global__ __launch_bounds__(256) void rpbexp_k(
    const float* __restrict__ rpb, unsigned* __restrict__ rpbE)
{
    int layer = blockIdx.x / 5, hp = blockIdx.x % 5;
    int tid = threadIdx.x;
    int q = tid >> 2, j0 = (tid & 3) * 16;
    const float* rsrc = rpb + layer * 2250 + hp * 2;
    unsigned* dst = rpbE + ((layer * 5 + hp) * 64 + q) * 64 + j0;
    int qr = q >> 3, qc = q & 7;
    #pragma unroll
    for (int jj = 0; jj < 16; jj++) {
        int j = j0 + jj;
        int jr = j >> 3, jc = j & 7;
        int ridx = ((qr - jr + 7) * 15 + (qc - jc + 7)) * 10;
        unsigned short lo = f2bf(rsrc[ridx] * 1.4426950409f);
        unsigned short hi = f2bf(rsrc[ridx + 1] * 1.4426950409f);
        dst[jj] = (unsigned)lo | ((unsigned)hi << 16);
    }
}

// ---------------------------------------------------------------- conv_in (implicit-GEMM MFMA)
__global__ __launch_bounds__(256) void conv_in_k(
    const float* __restrict__ x, const unsigned short* __restrict__ Wc,
    const float* __restrict__ bias, float* __restrict__ S)
{
    __shared__ __align__(16) unsigned short xt[10 * 42 * 32];  // 26880 B
    int b = blockIdx.x / 5, y0 = (blockIdx.x % 5) * 8;
    int tid = threadIdx.x;
    int lane = tid & 63, w = tid >> 6;
    int l15 = lane & 15, l4 = lane >> 4;

    uint4* xt4 = (uint4*)xt;
    for (int i = tid; i < 1680; i += 256) xt4[i] = make_uint4(0u, 0u, 0u, 0u);
    __syncthreads();

    const float* xb = x + (size_t)b * 28800;
    for (int idx = tid; idx < 10 * 18 * 40; idx += 256) {
        int xx = idx % 40;
        int rem = idx / 40;
        int ci = rem % 18;
        int ry = rem / 18;
        int yy = y0 + ry - 1;
        if (yy >= 0 && yy < 40) {
            float v = xb[ci * 1600 + yy * 40 + xx];
            int xs = xx + 1;
            int bo = (((ry * 42 + xs) * 32 + ci) * 2) ^ ((xs & 3) << 4);
            *(unsigned short*)((char*)xt + bo) = bfrn(v);
        }
    }
    __syncthreads();

    bf16x8 afr[9];
    #pragma unroll
    for (int g = 0; g < 9; g++)
        afr[g] = *(const bf16x8*)(Wc + (w * 9 + g) * 512 + lane * 8);

    int c0 = w * 16 + l4 * 4;
    bool valid = (c0 < 60);
    f4u bv = {0.f, 0.f, 0.f, 0.f};
    if (valid) bv = *(const f4u*)(bias + c0);
    const f32x4 zf = {0.f, 0.f, 0.f, 0.f};
    const char* xtb = (const char*)xt;

    for (int nt = 0; nt < 20; nt++) {
        int tok = nt * 16 + l15;
        int yl = tok / 40, xl = tok % 40;
        f32x4 acc = zf;
        #pragma unroll
        for (int g = 0; g < 9; g++) {
            int ky = g / 3, kx = g % 3;
            int xs = xl + kx;
            int ba = ((yl + ky) * 42 + xs) * 64 + ((l4 ^ (xs & 3)) << 4);
            bf16x8 bfrag = *(const bf16x8*)(xtb + ba);
            acc = MFMA16(afr[g], bfrag, acc);
        }
        if (valid) {
            float4 r;
            r.x = acc[0] + bv[0]; r.y = acc[1] + bv[1];
            r.z = acc[2] + bv[2]; r.w = acc[3] + bv[3];
            *(float4*)(S + ((size_t)b * 1600 + y0 * 40 + tok) * 60 + c0) = r;
        }
    }
}

// ---------------------------------------------------------------- fused Swin block
// LDS 38016 B -> 4 blocks/CU. x1 residual in regs. No manual lgkm drains (compiler
// inserts counted waits for same-wave P RAW); setprio(1) around head-loop MFMA.
template<int SHIFT>
__global__ __launch_bounds__(256, 4) void block_k(
    float* __restrict__ S,
    const unsigned short* __restrict__ WpL,
    const unsigned* __restrict__ rpE)
{
    __shared__ __align__(16) unsigned char LDSA[38016];
    unsigned short* xln = (unsigned short*)(LDSA + 0);
    unsigned short* Pl  = (unsigned short*)(LDSA + 0);
    unsigned short* h1  = (unsigned short*)(LDSA + 0);
    unsigned short* qn  = (unsigned short*)(LDSA + 9216);
    unsigned short* kn  = (unsigned short*)(LDSA + 18432);
    unsigned short* vt  = (unsigned short*)(LDSA + 27648);
    unsigned short* ln2 = (unsigned short*)(LDSA + 27648);

    const int tid = threadIdx.x;
    const int lane = tid & 63, w = tid >> 6;
    const int l15 = lane & 15, l4 = lane >> 4;
    const int wbase = w * 16;
    const int b = blockIdx.x / 25, wnd = blockIdx.x % 25;
    const int wh = wnd / 5, wc = wnd % 5;
    float* Sb = S + (size_t)b * 96000;
    const f32x4 zf = {0.f, 0.f, 0.f, 0.f};
    u32x4 zu = {0u, 0u, 0u, 0u};
    const bf16x8 zb = __builtin_bit_cast(bf16x8, zu);
    u32x4 ou = {0x3F803F80u, 0x3F803F80u, 0x3F803F80u, 0x3F803F80u};
    const bf16x8 ones = __builtin_bit_cast(bf16x8, ou);

    // ---- LN1 -> xln (bf16 n-major; col60=1 bias slot)
    {
        int n = tid >> 2, p = tid & 3, cb = p * 16;
        int g = gidx(n, wh, wc, SHIFT);
        const float* xp = Sb + (size_t)g * 60 + cb;
        float xv[16];
        {
            float4 v0 = *(const float4*)xp;
            float4 v1 = *(const float4*)(xp + 4);
            float4 v2 = *(const float4*)(xp + 8);
            xv[0] = v0.x; xv[1] = v0.y; xv[2] = v0.z; xv[3] = v0.w;
            xv[4] = v1.x; xv[5] = v1.y; xv[6] = v1.z; xv[7] = v1.w;
            xv[8] = v2.x; xv[9] = v2.y; xv[10] = v2.z; xv[11] = v2.w;
            if (p < 3) {
                float4 v3 = *(const float4*)(xp + 12);
                xv[12] = v3.x; xv[13] = v3.y; xv[14] = v3.z; xv[15] = v3.w;
            } else { xv[12] = xv[13] = xv[14] = xv[15] = 0.f; }
        }
        float s = 0.f;
        #pragma unroll
        for (int ii = 0; ii < 16; ii++) s += xv[ii];
        s += __shfl_xor(s, 1); s += __shfl_xor(s, 2);
        float mean = s * (1.f / 60.f);
        float vv = 0.f;
        #pragma unroll
        for (int ii = 0; ii < 12; ii++) { float d = xv[ii] - mean; vv += d * d; }
        #pragma unroll
        for (int ii = 12; ii < 16; ii++) { float d = xv[ii] - mean; vv += (p < 3) ? d * d : 0.f; }
        vv += __shfl_xor(vv, 1); vv += __shfl_xor(vv, 2);
        float rs = rsqrtf(vv * (1.f / 60.f) + 1e-5f);
        float ov[16];
        #pragma unroll
        for (int ii = 0; ii < 12; ii++) ov[ii] = (xv[ii] - mean) * rs;
        #pragma unroll
        for (int ii = 12; ii < 16; ii++)
            ov[ii] = (p < 3) ? (xv[ii] - mean) * rs : ((ii == 12) ? 1.f : 0.f);
        unsigned short* xr = xln + n * 72 + cb;
        *(uint4*)xr = make_uint4(pk2rn(ov[0], ov[1]), pk2rn(ov[2], ov[3]),
                                 pk2rn(ov[4], ov[5]), pk2rn(ov[6], ov[7]));
        *(uint4*)(xr + 8) = make_uint4(pk2rn(ov[8], ov[9]), pk2rn(ov[10], ov[11]),
                                       pk2rn(ov[12], ov[13]), pk2rn(ov[14], ov[15]));
    }
    __syncthreads();  // B1

    // ---- QKV (bias in k=60 slot; q pre-scaled)
    {
        bf16x8 bx[4][2];
        #pragma unroll
        for (int nt = 0; nt < 4; nt++)
            #pragma unroll
            for (int ks = 0; ks < 2; ks++)
                bx[nt][ks] = *(const bf16x8*)(xln + (nt * 16 + l15) * 72 + l4 * 8 + ks * 32);
        #pragma unroll
        for (int t = 0; t < 3; t++) {
            int ot = w * 3 + t;
            f32x4 acc[4];
            #pragma unroll
            for (int nt = 0; nt < 4; nt++) acc[nt] = zf;
            #pragma unroll
            for (int ks = 0; ks < 2; ks++) {
                bf16x8 a = *(const bf16x8*)(WpL + (ot * 2 + ks) * 512 + lane * 8);
                #pragma unroll
                for (int nt = 0; nt < 4; nt++) acc[nt] = MFMA16(a, bx[nt][ks], acc[nt]);
            }
            int o0 = ot * 16 + l4 * 4;
            #pragma unroll
            for (int nt = 0; nt < 4; nt++) {
                int n = nt * 16 + l15;
                if (o0 < 60) {
                    *(uint2*)(qn + n * 72 + o0) =
                        make_uint2(pk2rn(acc[nt][0], acc[nt][1]), pk2rn(acc[nt][2], acc[nt][3]));
                } else if (o0 < 120) {
                    *(uint2*)(kn + n * 72 + (o0 - 60)) =
                        make_uint2(pk2rn(acc[nt][0], acc[nt][1]), pk2rn(acc[nt][2], acc[nt][3]));
                } else {
                    int r = o0 - 120;
                    vt[(r + 0) * 72 + n] = bfrn(acc[nt][0]);
                    vt[(r + 1) * 72 + n] = bfrn(acc[nt][1]);
                    vt[(r + 2) * 72 + n] = bfrn(acc[nt][2]);
                    vt[(r + 3) * 72 + n] = bfrn(acc[nt][3]);
                }
            }
        }
    }
    __syncthreads();  // B2 (xln dead -> Pl writable)

    // ---- shift-mask bits
    unsigned maskbits = 0u;
    if (SHIFT) {
        int qtok = wbase + l15;
        int qr = qtok >> 3, qc = qtok & 7;
        int shp = wh * 8 + qr, swp = wc * 8 + qc;
        int qreg = (shp < 32 ? 0 : (shp < 36 ? 1 : 2)) * 3 + (swp < 32 ? 0 : (swp < 36 ? 1 : 2));
        #pragma unroll
        for (int e = 0; e < 16; e++) {
            int jt = e >> 2, r = e & 3;
            int j = jt * 16 + l4 * 4 + r;
            int jr = j >> 3, jc = j & 7;
            int shq = wh * 8 + jr, swq = wc * 8 + jc;
            int jreg = (shq < 32 ? 0 : (shq < 36 ? 1 : 2)) * 3 + (swq < 32 ? 0 : (swq < 36 ? 1 : 2));
            if (jreg != qreg) maskbits |= (1u << e);
        }
    }

    // ---- head loop (per-wave P rows; compiler-counted LDS waits; setprio on MFMA)
    f32x4 oacc[10];
    #pragma unroll
    for (int h = 0; h < 10; h++) oacc[h] = zf;
    unsigned short* prow = Pl + (wbase + l15) * 72;
    const unsigned* rpq = rpE + ((wbase + l15) << 6) + (l4 << 2);

    u32x4 rpc[4];
    #pragma unroll
    for (int jt = 0; jt < 4; jt++) rpc[jt] = *(const u32x4*)(rpq + jt * 16);

    #pragma unroll
    for (int hp = 0; hp < 5; hp++) {
        u32x4 rpn[4];
        if (hp < 4) {
            const unsigned* rq = rpq + (hp + 1) * 4096;
            #pragma unroll
            for (int jt = 0; jt < 4; jt++) rpn[jt] = *(const u32x4*)(rq + jt * 16);
        }
        #pragma unroll
        for (int hh2 = 0; hh2 < 2; hh2++) {
            const int h = hp * 2 + hh2;
            bf16x8 bq = zb, ak0 = zb, ak1 = zb, ak2 = zb, ak3 = zb;
            if (l4 == 0) {
                const unsigned* qp = (const unsigned*)(qn + (wbase + l15) * 72 + h * 6);
                u32x4 uq = {qp[0], qp[1], qp[2], 0u};
                bq = __builtin_bit_cast(bf16x8, uq);
                const unsigned* k0p = (const unsigned*)(kn + (0 * 16 + l15) * 72 + h * 6);
                const unsigned* k1p = (const unsigned*)(kn + (1 * 16 + l15) * 72 + h * 6);
                const unsigned* k2p = (const unsigned*)(kn + (2 * 16 + l15) * 72 + h * 6);
                const unsigned* k3p = (const unsigned*)(kn + (3 * 16 + l15) * 72 + h * 6);
                u32x4 u0 = {k0p[0], k0p[1], k0p[2], 0u}; ak0 = __builtin_bit_cast(bf16x8, u0);
                u32x4 u1 = {k1p[0], k1p[1], k1p[2], 0u}; ak1 = __builtin_bit_cast(bf16x8, u1);
                u32x4 u2 = {k2p[0], k2p[1], k2p[2], 0u}; ak2 = __builtin_bit_cast(bf16x8, u2);
                u32x4 u3 = {k3p[0], k3p[1], k3p[2], 0u}; ak3 = __builtin_bit_cast(bf16x8, u3);
            }
            __builtin_amdgcn_s_setprio(1);
            f32x4 s0 = MFMA16(ak0, bq, zf);
            f32x4 s1 = MFMA16(ak1, bq, zf);
            f32x4 s2 = MFMA16(ak2, bq, zf);
            f32x4 s3 = MFMA16(ak3, bq, zf);
            __builtin_amdgcn_s_setprio(0);
            float ee[16];
            #pragma unroll
            for (int r = 0; r < 4; r++) {
                ee[0 + r]  = __builtin_amdgcn_exp2f(s0[r] + bfsel(rpc[0][r], hh2));
                ee[4 + r]  = __builtin_amdgcn_exp2f(s1[r] + bfsel(rpc[1][r], hh2));
                ee[8 + r]  = __builtin_amdgcn_exp2f(s2[r] + bfsel(rpc[2][r], hh2));
                ee[12 + r] = __builtin_amdgcn_exp2f(s3[r] + bfsel(rpc[3][r], hh2));
            }
            if (SHIFT) {
                #pragma unroll
                for (int e = 0; e < 16; e++)
                    if (maskbits & (1u << e)) ee[e] = 0.f;
            }
            #pragma unroll
            for (int jt = 0; jt < 4; jt++)
                *(uint2*)(prow + jt * 16 + l4 * 4) =
                    make_uint2(pk2rn(ee[jt * 4 + 0], ee[jt * 4 + 1]),
                               pk2rn(ee[jt * 4 + 2], ee[jt * 4 + 3]));
            // compiler inserts the counted lgkm wait for the same-wave P RAW
            bf16x8 ap0 = *(const bf16x8*)(prow + l4 * 8);
            bf16x8 ap1 = *(const bf16x8*)(prow + 32 + l4 * 8);
            bf16x8 bv0 = *(const bf16x8*)(vt + (h * 6 + l15) * 72 + l4 * 8);
            bf16x8 bv1 = *(const bf16x8*)(vt + (h * 6 + l15) * 72 + 32 + l4 * 8);
            __builtin_amdgcn_s_setprio(1);
            f32x4 sm = MFMA16(ap0, ones, zf);
            sm = MFMA16(ap1, ones, sm);
            f32x4 pv = MFMA16(ap0, bv0, zf);
            pv = MFMA16(ap1, bv1, pv);
            __builtin_amdgcn_s_setprio(0);
            #pragma unroll
            for (int r = 0; r < 4; r++)
                oacc[h][r] = pv[r] * __builtin_amdgcn_rcpf(sm[r]);
        }
        #pragma unroll
        for (int jt = 0; jt < 4; jt++) rpc[jt] = rpn[jt];
    }

    // ---- attention out -> olds (=qn slab; own-wave rows only)
    unsigned short* olds = qn;
    if (l15 < 6) {
        #pragma unroll
        for (int h = 0; h < 10; h++)
            #pragma unroll
            for (int j = 0; j < 4; j++)
                olds[(wbase + l4 * 4 + j) * 72 + h * 6 + l15] = bfrn(oacc[h][j]);
    } else if (l15 < 10) {
        unsigned short pv16 = (l15 == 6) ? (unsigned short)0x3F80 : (unsigned short)0;
        #pragma unroll
        for (int j = 0; j < 4; j++)
            olds[(wbase + l4 * 4 + j) * 72 + 60 + (l15 - 6)] = pv16;
    }
    __syncthreads();  // B2.5: all waves past Pl/vt/kn reads -> ln2 overlay safe

    // ---- proj + residual -> x1 in REGISTERS (token n=wbase+l15, ch c=ot*16+l4*4+r)
    f32x4 x1v[4];
    {
        bf16x8 bo0 = *(const bf16x8*)(olds + (wbase + l15) * 72 + l4 * 8);
        bf16x8 bo1 = *(const bf16x8*)(olds + (wbase + l15) * 72 + 32 + l4 * 8);
        f32x4 acc[4];
        #pragma unroll
        for (int ot = 0; ot < 4; ot++) acc[ot] = zf;
        #pragma unroll
        for (int ot = 0; ot < 4; ot++) {
            bf16x8 a0 = *(const bf16x8*)(WpL + 12288 + (ot * 2 + 0) * 512 + lane * 8);
            bf16x8 a1 = *(const bf16x8*)(WpL + 12288 + (ot * 2 + 1) * 512 + lane * 8);
            acc[ot] = MFMA16(a0, bo0, acc[ot]);
            acc[ot] = MFMA16(a1, bo1, acc[ot]);
        }
        int n = wbase + l15;
        int g = gidx(n, wh, wc, SHIFT);
        #pragma unroll
        for (int ot = 0; ot < 4; ot++) {
            int o0 = ot * 16 + l4 * 4;
            if (o0 < 60) {
                float4 xr = *(const float4*)(Sb + (size_t)g * 60 + o0);
                x1v[ot][0] = xr.x + acc[ot][0];
                x1v[ot][1] = xr.y + acc[ot][1];
                x1v[ot][2] = xr.z + acc[ot][2];
                x1v[ot][3] = xr.w + acc[ot][3];
            } else {
                x1v[ot] = zf;
            }
        }
    }

    // ---- LN2 in registers -> ln2 (bf16)
    {
        float s = 0.f;
        #pragma unroll
        for (int ot = 0; ot < 4; ot++)
            #pragma unroll
            for (int r = 0; r < 4; r++) s += x1v[ot][r];
        s += __shfl_xor(s, 16); s += __shfl_xor(s, 32);
        float mean = s * (1.f / 60.f);
        float vv = 0.f;
        #pragma unroll
        for (int ot = 0; ot < 4; ot++) {
            int o0 = ot * 16 + l4 * 4;
            if (o0 < 60) {
                #pragma unroll
                for (int r = 0; r < 4; r++) { float d = x1v[ot][r] - mean; vv += d * d; }
            }
        }
        vv += __shfl_xor(vv, 16); vv += __shfl_xor(vv, 32);
        float rs = rsqrtf(vv * (1.f / 60.f) + 1e-5f);
        int n = wbase + l15;
        #pragma unroll
        for (int ot = 0; ot < 4; ot++) {
            int o0 = ot * 16 + l4 * 4;
            if (o0 < 60) {
                *(uint2*)(ln2 + n * 72 + o0) = make_uint2(
                    pk2rn((x1v[ot][0] - mean) * rs, (x1v[ot][1] - mean) * rs),
                    pk2rn((x1v[ot][2] - mean) * rs, (x1v[ot][3] - mean) * rs));
            } else {
                *(uint2*)(ln2 + n * 72 + 60) = make_uint2(0x00003F80u, 0u);  // bias=1, pad 0
            }
        }
    }
    __syncthreads();  // B3 (ln2 ready; Pl/olds dead -> h1 overlay safe)

    // ---- MLP (x1 stays in regs for the final residual)
    f32x4 acc2[4];
    #pragma unroll
    for (int ot = 0; ot < 4; ot++) acc2[ot] = zf;

    #pragma unroll
    for (int ph = 0; ph < 2; ph++) {
        {
            bf16x8 bl[4][2];
            #pragma unroll
            for (int nt = 0; nt < 4; nt++)
                #pragma unroll
                for (int ks = 0; ks < 2; ks++)
                    bl[nt][ks] = *(const bf16x8*)(ln2 + (nt * 16 + l15) * 72 + l4 * 8 + ks * 32);
            #pragma unroll
            for (int t = 0; t < 2; t++) {
                int ot = w + t * 4;
                f32x4 a1[4];
                #pragma unroll
                for (int nt = 0; nt < 4; nt++) a1[nt] = zf;
                #pragma unroll
                for (int ks = 0; ks < 2; ks++) {
                    bf16x8 a = *(const bf16x8*)(WpL + 16384 + ((ph * 8 + ot) * 2 + ks) * 512 + lane * 8);
                    #pragma unroll
                    for (int nt = 0; nt < 4; nt++) a1[nt] = MFMA16(a, bl[nt][ks], a1[nt]);
                }
                int o0 = ot * 16 + l4 * 4;
                if (o0 < 120) {
                    #pragma unroll
                    for (int nt = 0; nt < 4; nt++) {
                        int n = nt * 16 + l15;
                        *(uint2*)(h1 + n * 136 + o0) =
                            make_uint2(pk2rn(gelu_f(a1[nt][0]), gelu_f(a1[nt][1])),
                                       pk2rn(gelu_f(a1[nt][2]), gelu_f(a1[nt][3])));
                    }
                }
            }
            if (ph == 0 && tid < 64)
                *(uint4*)(h1 + tid * 136 + 120) = make_uint4(0x3F80u, 0u, 0u, 0u);
        }
        __syncthreads();
        {
            bf16x8 bh[4];
            #pragma unroll
            for (int ks = 0; ks < 4; ks++)
                bh[ks] = *(const bf16x8*)(h1 + (wbase + l15) * 136 + l4 * 8 + ks * 32);
            #pragma unroll
            for (int ot = 0; ot < 4; ot++)
                #pragma unroll
                for (int ks = 0; ks < 4; ks++) {
                    bf16x8 a = *(const bf16x8*)(WpL + 32768 + ((ph * 4 + ot) * 4 + ks) * 512 + lane * 8);
                    acc2[ot] = MFMA16(a, bh[ks], acc2[ot]);
                }
        }
        if (ph == 0) __syncthreads();
    }

    // ---- final: S[g] = x1(reg) + fc2out
    {
        int n = wbase + l15;
        int g = gidx(n, wh, wc, SHIFT);
        #pragma unroll
        for (int ot = 0; ot < 4; ot++) {
            int o0 = ot * 16 + l4 * 4;
            if (o0 < 60) {
                float4 r;
                r.x = x1v[ot][0] + acc2[ot][0];
                r.y = x1v[ot][1] + acc2[ot][1];
                r.z = x1v[ot][2] + acc2[ot][2];
                r.w = x1v[ot][3] + acc2[ot][3];
                *(float4*)(Sb + (size_t)g * 60 + o0) = r;
            }
        }
    }
}

// ---------------------------------------------------------------- conv_out (implicit-GEMM MFMA)
__global__ __launch_bounds__(256) void conv_out_k(
    const float* __restrict__ S, const unsigned short* __restrict__ Wc2,
    const float* __restrict__ bias, float* __restrict__ out)
{
    __shared__ __align__(16) unsigned short st[6 * 42 * 64];  // 32256 B
    int b = blockIdx.x / 10, y0 = (blockIdx.x % 10) * 4;
    int tid = threadIdx.x;
    int lane = tid & 63, w = tid >> 6;
    int l15 = lane & 15, l4 = lane >> 4;

    uint4* st4 = (uint4*)st;
    for (int i = tid; i < 2016; i += 256) st4[i] = make_uint4(0u, 0u, 0u, 0u);
    __syncthreads();

    const float* Sb = S + (size_t)b * 96000;
    for (int idx = tid; idx < 3600; idx += 256) {
        int cg = idx % 15;
        int xx = (idx / 15) % 40;
        int ry = idx / 600;
        int yy = y0 + ry - 1;
        if (yy >= 0 && yy < 40) {
            const float* sp = Sb + ((size_t)yy * 40 + xx) * 60 + cg * 4;
            float4 v = *(const float4*)sp;
            int xs = xx + 1;
            int bo = (ry * 42 + xs) * 128 + ((cg * 8) ^ ((xs & 7) << 4));
            *(uint2*)((char*)st + bo) = make_uint2(pk2rn(v.x, v.y), pk2rn(v.z, v.w));
        }
    }
    __syncthreads();

    bf16x8 afr[9][2];
    #pragma unroll
    for (int g = 0; g < 9; g++)
        #pragma unroll
        for (int ks = 0; ks < 2; ks++)
            afr[g][ks] = *(const bf16x8*)(Wc2 + (g * 2 + ks) * 512 + lane * 8);

    float b0 = bias[0], b1 = bias[1], b2 = bias[2];
    const f32x4 zf = {0.f, 0.f, 0.f, 0.f};
    const char* stb = (const char*)st;

    for (int nt = w; nt < 10; nt += 4) {
        int tok = nt * 16 + l15;
        int yl = tok / 40, xl = tok % 40;
        f32x4 acc = zf;
        #pragma unroll
        for (int g = 0; g < 9; g++) {
            int ky = g / 3, kx = g % 3;
            int xs = xl + kx;
            int base = ((yl + ky) * 42 + xs) * 128;
            #pragma unroll
            for (int ks = 0; ks < 2; ks++) {
                int bo = base + (((ks * 4 + l4) ^ (xs & 7)) << 4);
                bf16x8 bfrag = *(const bf16x8*)(stb + bo);
                acc = MFMA16(afr[g][ks], bfrag, acc);
            }
        }
        if (l4 == 0) {
            int y = y0 + yl;
            float* op = out + (size_t)b * 4800 + y * 40 + xl;
            op[0] = acc[0] + b0;
            op[1600] = acc[1] + b1;
            op[3200] = acc[2] + b2;
        }
    }
}

// ---------------------------------------------------------------- launch
extern "C" void kernel_launch(void* const* d_in, const int* in_sizes, int n_in,
                              void* d_out, int out_size, void* d_ws, size_t ws_size,
                              hipStream_t stream)
{
    const float* x   = (const float*)d_in[0];
    const float* ciw = (const float*)d_in[1];
    const float* cib = (const float*)d_in[2];
    const float* n1g = (const float*)d_in[3];
    const float* n1b = (const float*)d_in[4];
    const float* qw  = (const float*)d_in[5];
    const float* qb  = (const float*)d_in[6];
    const float* rpb = (const float*)d_in[7];
    const float* pw  = (const float*)d_in[8];
    const float* pb  = (const float*)d_in[9];
    const float* n2g = (const float*)d_in[10];
    const float* n2b = (const float*)d_in[11];
    const float* f1w = (const float*)d_in[12];
    const float* f1b = (const float*)d_in[13];
    const float* f2w = (const float*)d_in[14];
    const float* f2b = (const float*)d_in[15];
    const float* cow = (const float*)d_in[16];
    const float* cob = (const float*)d_in[17];
    float* out = (float*)d_out;
    float* S = (float*)d_ws;                                        // 49,152,000 B
    unsigned short* Wp = (unsigned short*)((char*)d_ws + 49152000); // packed weights
    unsigned* rpbE = (unsigned*)((char*)d_ws + 49545216);           // expanded rpb
    unsigned short* Wc = (unsigned short*)((char*)d_ws + 49872896); // conv A-frags

    prep_k<<<96, 256, 0, stream>>>(qw, pw, f1w, f2w, qb, pb, f1b, f2b,
                                   n1g, n1b, n2g, n2b, Wp);
    prepc_k<<<14, 256, 0, stream>>>(ciw, cow, Wc);
    rpbexp_k<<<20, 256, 0, stream>>>(rpb, rpbE);
    conv_in_k<<<128 * 5, 256, 0, stream>>>(x, Wc, cib, S);
    for (int i = 0; i < 4; i++) {
        const unsigned short* WpL = Wp + i * 49152;
        const unsigned* rpEL = rpbE + i * 5 * 4096;
        if (i & 1) block_k<4><<<128 * 25, 256, 0, stream>>>(S, WpL, rpEL);
        else       block_k<0><<<128 * 25, 256, 0, stream>>>(S, WpL, rpEL);
    }
    conv_out_k<<<128 * 10, 256, 0, stream>>>(S, Wc + 36 * 512, cob, out);
}